// Round 8
// baseline (97.182 us; speedup 1.0000x reference)
//
#include <hip/hip_runtime.h>

// DAS beamforming: out[b,z,x,k] = sum_c lerp(rf[b,c], delay(b,c,z,x))[k]
// Round 8: attack the REAL limiter found in R5/R7 post-mortems: barrier/latency
// stalls (pipes ~40% idle; LDS busy only ~2.5k of ~6k cyc/phase/CU).
//  - 512-thread blocks, 4 blocks/CU (1024 blocks): 4 independent barrier
//    domains per CU -- one block's stage-drain overlaps three others' gathers.
//  - fp16-in-LDS (R7): 16 B/pair gathers (ds_read2_b64), dbuf 2x16 KiB =
//    32 KiB/block. In-kernel cvt, staged registers consumed immediately
//    (R6's spill lesson); __launch_bounds__(512,8) caps at 64 VGPR, body
//    needs ~48 peak.
//  - epilogue: disjoint partials to ws + reduce kernel (R4: contended atomics
//    ping-pong across XCDs; R3: never READ pre-poisoned ws data -- partials
//    are written then read within one replay, L2-warm).

#define NBATCH 2
#define NC 128
#define NS 2048
#define NK 4
#define NM 65536                              // Nz*Nx pixels per batch

#define THREADS 512
#define PX_PER_THREAD 2
#define PX_PER_BLOCK (THREADS * PX_PER_THREAD)   // 1024
#define C_PER_BLOCK 16
#define N_CHUNKS (NC / C_PER_BLOCK)           // 8
#define N_TILES (NM / PX_PER_BLOCK)           // 64
#define NBLOCKS (NBATCH * N_TILES * N_CHUNKS) // 1024 = 4 blocks/CU, 32 waves/CU

#define CH_F (NS * NK)                        // 8192 floats = 32 KiB fp32/channel
#define CH_H (NS * NK)                        // 8192 halves = 16 KiB fp16/channel

#define PART_BYTES ((size_t)N_CHUNKS * NBATCH * NM * NK * 4)  // 16.8 MB

typedef __attribute__((ext_vector_type(4))) _Float16 half4;
typedef __attribute__((ext_vector_type(8))) _Float16 half8;

// Load one channel slice (8192 floats) with 4 fully-coalesced float4 loads per
// thread (512 thr), convert to fp16, write as 2x 16-B LDS stores. All staged
// registers die inside this function (no spill pressure).
__device__ __forceinline__ void stage_cvt(const float* slice, _Float16* buf, int t) {
    const float4* src = (const float4*)slice;
#pragma unroll
    for (int r = 0; r < 2; ++r) {
        const float4 a = src[2 * (r * THREADS + t)];
        const float4 b = src[2 * (r * THREADS + t) + 1];
        half8 h;
        h[0] = (_Float16)a.x; h[1] = (_Float16)a.y;
        h[2] = (_Float16)a.z; h[3] = (_Float16)a.w;
        h[4] = (_Float16)b.x; h[5] = (_Float16)b.y;
        h[6] = (_Float16)b.z; h[7] = (_Float16)b.w;
        *(half8*)(buf + 8 * (r * THREADS + t)) = h;   // 16-B ds_write_b128
    }
}

template <bool ATOMIC>
__global__ __launch_bounds__(THREADS, 8) void das_kernel(
    const float* __restrict__ rf, const float* __restrict__ g,
    const float* __restrict__ pr, const float* __restrict__ p,
    float* __restrict__ dst)    // ATOMIC ? out : partials in ws
{
    __shared__ alignas(16) _Float16 sbuf[2][CH_H];   // 2 x 16 KiB fp16 dbuf

    const int bid   = blockIdx.x;
    const int chunk = bid & (N_CHUNKS - 1);
    const int tile  = (bid >> 3) & (N_TILES - 1);
    const int b     = bid >> 9;
    const int t     = threadIdx.x;
    const int px0   = tile * PX_PER_BLOCK;

    const float c0v = p[b * 4 + 0];
    const float fsv = p[b * 4 + 1];
    const float t0v = p[b * 4 + 2];
    const float scale = fsv / c0v;            // samples per meter
    const float sb0   = scale * t0v;

    float gx[PX_PER_THREAD], gy[PX_PER_THREAD], gzv[PX_PER_THREAD], sbase[PX_PER_THREAD];
#pragma unroll
    for (int j = 0; j < PX_PER_THREAD; ++j) {
        const int m = px0 + j * THREADS + t;
        const float* gp = g + ((size_t)b * NM + m) * 3;
        gx[j]  = gp[0];
        gy[j]  = gp[1];
        gzv[j] = gp[2];
        sbase[j] = sb0 + scale * gzv[j];      // fs*(t0 + d_tx)/c0 hoisted
    }

    float4 acc[PX_PER_THREAD];
#pragma unroll
    for (int j = 0; j < PX_PER_THREAD; ++j) acc[j] = make_float4(0.f, 0.f, 0.f, 0.f);

    const int ch0 = chunk * C_PER_BLOCK;
    const float* slice0 = rf + (size_t)(b * NC + ch0) * CH_F;

    // Prologue: stage channel 0
    stage_cvt(slice0, &sbuf[0][0], t);
    __syncthreads();

    for (int ph = 0; ph < C_PER_BLOCK; ++ph) {
        // Stage channel ph+1 into the other buffer (consumed immediately; the
        // barrier ending phase ph-1 separated these writes from prior reads).
        // This wave's load latency overlaps the other 3 blocks' gathers.
        if (ph + 1 < C_PER_BLOCK)
            stage_cvt(slice0 + (size_t)(ph + 1) * CH_F, &sbuf[(ph + 1) & 1][0], t);

        const _Float16* lc = &sbuf[ph & 1][0];
        const float* prp = pr + ((size_t)(b * NC + ch0 + ph)) * 3;
        const float prx = prp[0], pry = prp[1], prz = prp[2];

#pragma unroll
        for (int j = 0; j < PX_PER_THREAD; ++j) {
            const float dx = gx[j]  - prx;
            const float dy = gy[j]  - pry;
            const float dz = gzv[j] - prz;
            const float drx = __builtin_amdgcn_sqrtf(fmaf(dx, dx, fmaf(dy, dy, dz * dz)));
            float s = fmaf(scale, drx, sbase[j]);         // frac sample idx
            s = fminf(fmaxf(s, 0.0f), (float)(NS - 1));
            const float fi = fminf(floorf(s), (float)(NS - 2));
            const float w  = s - fi;
            const float wm = 1.0f - w;
            const int i0 = (int)fi;
            // two adjacent 8-B fp16 quads -> single ds_read2_b64
            const half4 y0 = *(const half4*)(lc + i0 * 4);
            const half4 y1 = *(const half4*)(lc + i0 * 4 + 4);
            acc[j].x = fmaf((float)y0[0], wm, fmaf((float)y1[0], w, acc[j].x));
            acc[j].y = fmaf((float)y0[1], wm, fmaf((float)y1[1], w, acc[j].y));
            acc[j].z = fmaf((float)y0[2], wm, fmaf((float)y1[2], w, acc[j].z));
            acc[j].w = fmaf((float)y0[3], wm, fmaf((float)y1[3], w, acc[j].w));
        }
        __syncthreads();
    }

    if (ATOMIC) {
        float* ob = dst + (size_t)b * NM * NK;
#pragma unroll
        for (int j = 0; j < PX_PER_THREAD; ++j) {
            const int m = px0 + j * THREADS + t;
            float* op = ob + (size_t)m * NK;
            atomicAdd(op + 0, acc[j].x);
            atomicAdd(op + 1, acc[j].y);
            atomicAdd(op + 2, acc[j].z);
            atomicAdd(op + 3, acc[j].w);
        }
    } else {
        // partial[chunk][b][m] as float4 — disjoint per block, plain stores
        float4* pw = (float4*)dst + (size_t)(chunk * NBATCH + b) * NM;
#pragma unroll
        for (int j = 0; j < PX_PER_THREAD; ++j) {
            const int m = px0 + j * THREADS + t;
            pw[m] = acc[j];
        }
    }
}

// out[i] = sum over 8 chunk partials; i indexes float4 over [B*NM)
__global__ __launch_bounds__(256) void reduce_kernel(
    const float4* __restrict__ part, float4* __restrict__ out)
{
    const int i = blockIdx.x * 256 + threadIdx.x;
    const size_t stride = (size_t)NBATCH * NM;
    float4 a = part[i];
#pragma unroll
    for (int c = 1; c < N_CHUNKS; ++c) {
        const float4 v = part[c * stride + i];
        a.x += v.x; a.y += v.y; a.z += v.z; a.w += v.w;
    }
    out[i] = a;
}

extern "C" void kernel_launch(void* const* d_in, const int* in_sizes, int n_in,
                              void* d_out, int out_size, void* d_ws, size_t ws_size,
                              hipStream_t stream) {
    (void)in_sizes; (void)n_in;
    const float* rf = (const float*)d_in[0];
    const float* g  = (const float*)d_in[1];
    const float* pr = (const float*)d_in[2];
    const float* p  = (const float*)d_in[3];
    float* out = (float*)d_out;

    if (ws_size >= PART_BYTES) {
        das_kernel<false><<<NBLOCKS, THREADS, 0, stream>>>(rf, g, pr, p, (float*)d_ws);
        reduce_kernel<<<(NBATCH * NM) / 256, 256, 0, stream>>>((const float4*)d_ws,
                                                               (float4*)out);
    } else {
        hipMemsetAsync(d_out, 0, (size_t)out_size * sizeof(float), stream);
        das_kernel<true><<<NBLOCKS, THREADS, 0, stream>>>(rf, g, pr, p, out);
    }
}

// Round 9
// 87.768 us; speedup vs baseline: 1.1073x; 1.1073x over previous
//
#include <hip/hip_runtime.h>

// DAS beamforming: out[b,z,x,k] = sum_c lerp(rf[b,c], delay(b,c,z,x))[k]
// Round 9 = R5 (best measured) + ILP depth. Evidence from R2/R5/R7/R8:
//  - TLP 16 vs 32 waves ~ wash; fp16-in-LDS ~ wash-to-negative (cvt VALU
//    eats the LDS saving; SQ_LDS_BANK_CONFLICT is 4.25M REGARDLESS of gather
//    width or geometry -- fixed by the data's address pattern).
//  - Never tried: deeper per-thread ILP. Here: 512 thr x 4 px/thread = 4
//    independent sqrt->addr->ds_read chains between barriers (2x R5), half
//    the waves per barrier convoy.
//  - fp32 + global_load_lds dbuf staging: zero VALU staging, no cvts.
//  - __launch_bounds__(512,4) -> 128 VGPR cap: compiler can pipeline all 4
//    pixels' 32-B fragments without spilling (R6 lesson). Occupancy is
//    LDS-capped at 2 blocks/CU (2 x 64 KiB) = 16 waves/CU regardless.
//  - epilogue: disjoint partials to ws + reduce (R4: contended atomics
//    cross-XCD ping-pong; R3: never READ pre-poisoned ws -- partials are
//    write-then-read within one replay, L2-warm). Partials stay 16.8 MB.

#define NBATCH 2
#define NC 128
#define NS 2048
#define NK 4
#define NM 65536                              // Nz*Nx pixels per batch

#define THREADS 512
#define PX_PER_THREAD 4
#define PX_PER_BLOCK (THREADS * PX_PER_THREAD)   // 2048
#define C_PER_BLOCK 16
#define N_CHUNKS (NC / C_PER_BLOCK)           // 8
#define N_TILES (NM / PX_PER_BLOCK)           // 32
#define NBLOCKS (NBATCH * N_TILES * N_CHUNKS) // 512 = 2 blocks/CU
#define SLICE_F4 (NS * NK / 4)                // 2048 float4 = 32 KiB / channel

#define PART_BYTES ((size_t)N_CHUNKS * NBATCH * NM * NK * 4)  // 16.8 MB

// Stage one channel slice (32 KiB) global->LDS async: 4 x 16 B per thread,
// lane-sequential LDS dest as the HW requires. Zero VALU data movement.
__device__ __forceinline__ void stage_channel(const float* slice, float4* lbuf, int t) {
#pragma unroll
    for (int r = 0; r < SLICE_F4 / THREADS; ++r) {
        const int d = r * THREADS + t;
        __builtin_amdgcn_global_load_lds(
            (const __attribute__((address_space(1))) void*)(slice + (size_t)d * 4),
            (__attribute__((address_space(3))) void*)(lbuf + d),
            16, 0, 0);
    }
}

template <bool ATOMIC>
__global__ __launch_bounds__(THREADS, 4) void das_kernel(
    const float* __restrict__ rf, const float* __restrict__ g,
    const float* __restrict__ pr, const float* __restrict__ p,
    float* __restrict__ dst)    // ATOMIC ? out : partials in ws
{
    __shared__ float4 sbuf[2][SLICE_F4];   // 2 x 32 KiB double buffer

    const int bid   = blockIdx.x;
    const int chunk = bid & (N_CHUNKS - 1);
    const int tile  = (bid >> 3) & (N_TILES - 1);
    const int b     = bid >> 8;
    const int t     = threadIdx.x;
    const int px0   = tile * PX_PER_BLOCK;

    const float c0v = p[b * 4 + 0];
    const float fsv = p[b * 4 + 1];
    const float t0v = p[b * 4 + 2];
    const float scale = fsv / c0v;            // samples per meter
    const float sb0   = scale * t0v;

    float gx[PX_PER_THREAD], gy[PX_PER_THREAD], gzv[PX_PER_THREAD], sbase[PX_PER_THREAD];
#pragma unroll
    for (int j = 0; j < PX_PER_THREAD; ++j) {
        const int m = px0 + j * THREADS + t;
        const float* gp = g + ((size_t)b * NM + m) * 3;
        gx[j]  = gp[0];
        gy[j]  = gp[1];
        gzv[j] = gp[2];
        sbase[j] = sb0 + scale * gzv[j];      // fs*(t0 + d_tx)/c0 hoisted
    }

    float4 acc[PX_PER_THREAD];
#pragma unroll
    for (int j = 0; j < PX_PER_THREAD; ++j) acc[j] = make_float4(0.f, 0.f, 0.f, 0.f);

    const int ch0 = chunk * C_PER_BLOCK;
    const float* slice0 = rf + (size_t)(b * NC + ch0) * NS * NK;

    stage_channel(slice0, &sbuf[0][0], t);

    for (int cc = 0; cc < C_PER_BLOCK; ++cc) {
        // vmcnt(0)+barrier: drains the stage into sbuf[cc&1] and protects
        // sbuf[(cc+1)&1] from overwrite while still being read. The stage for
        // cc+1 (issued below) has the whole gather phase to complete; the
        // co-resident block computes through this block's drain.
        __syncthreads();
        if (cc + 1 < C_PER_BLOCK)
            stage_channel(slice0 + (size_t)(cc + 1) * NS * NK,
                          &sbuf[(cc + 1) & 1][0], t);

        const float4* lb = &sbuf[cc & 1][0];
        const float* prp = pr + ((size_t)(b * NC + ch0 + cc)) * 3;
        const float prx = prp[0], pry = prp[1], prz = prp[2];

        // 4 independent gather chains; compiler has 128-VGPR headroom to
        // front-load all 8 ds_read_b128 and pipeline the lerps.
#pragma unroll
        for (int j = 0; j < PX_PER_THREAD; ++j) {
            const float dx = gx[j]  - prx;
            const float dy = gy[j]  - pry;
            const float dz = gzv[j] - prz;
            const float drx = __builtin_amdgcn_sqrtf(fmaf(dx, dx, fmaf(dy, dy, dz * dz)));
            float s = fmaf(scale, drx, sbase[j]);         // frac sample idx
            s = fminf(fmaxf(s, 0.0f), (float)(NS - 1));   // clamp
            const float fi = fminf(floorf(s), (float)(NS - 2));
            const float w  = s - fi;
            const float wm = 1.0f - w;
            const int i0 = (int)fi;
            const float4 y0 = lb[i0];                     // adjacent 32 B:
            const float4 y1 = lb[i0 + 1];                 // 2x ds_read_b128
            acc[j].x = fmaf(y0.x, wm, fmaf(y1.x, w, acc[j].x));
            acc[j].y = fmaf(y0.y, wm, fmaf(y1.y, w, acc[j].y));
            acc[j].z = fmaf(y0.z, wm, fmaf(y1.z, w, acc[j].z));
            acc[j].w = fmaf(y0.w, wm, fmaf(y1.w, w, acc[j].w));
        }
    }

    if (ATOMIC) {
        float* ob = dst + (size_t)b * NM * NK;
#pragma unroll
        for (int j = 0; j < PX_PER_THREAD; ++j) {
            const int m = px0 + j * THREADS + t;
            float* op = ob + (size_t)m * NK;
            atomicAdd(op + 0, acc[j].x);
            atomicAdd(op + 1, acc[j].y);
            atomicAdd(op + 2, acc[j].z);
            atomicAdd(op + 3, acc[j].w);
        }
    } else {
        // partial[chunk][b][m] as float4 — disjoint per block, plain stores
        float4* pw = (float4*)dst + (size_t)(chunk * NBATCH + b) * NM;
#pragma unroll
        for (int j = 0; j < PX_PER_THREAD; ++j) {
            const int m = px0 + j * THREADS + t;
            pw[m] = acc[j];
        }
    }
}

// out[i] = sum over 8 chunk partials; i indexes float4 over [B*NM)
__global__ __launch_bounds__(256) void reduce_kernel(
    const float4* __restrict__ part, float4* __restrict__ out)
{
    const int i = blockIdx.x * 256 + threadIdx.x;
    const size_t stride = (size_t)NBATCH * NM;
    float4 a = part[i];
#pragma unroll
    for (int c = 1; c < N_CHUNKS; ++c) {
        const float4 v = part[c * stride + i];
        a.x += v.x; a.y += v.y; a.z += v.z; a.w += v.w;
    }
    out[i] = a;
}

extern "C" void kernel_launch(void* const* d_in, const int* in_sizes, int n_in,
                              void* d_out, int out_size, void* d_ws, size_t ws_size,
                              hipStream_t stream) {
    (void)in_sizes; (void)n_in;
    const float* rf = (const float*)d_in[0];
    const float* g  = (const float*)d_in[1];
    const float* pr = (const float*)d_in[2];
    const float* p  = (const float*)d_in[3];
    float* out = (float*)d_out;

    if (ws_size >= PART_BYTES) {
        das_kernel<false><<<NBLOCKS, THREADS, 0, stream>>>(rf, g, pr, p, (float*)d_ws);
        reduce_kernel<<<(NBATCH * NM) / 256, 256, 0, stream>>>((const float4*)d_ws,
                                                               (float4*)out);
    } else {
        hipMemsetAsync(d_out, 0, (size_t)out_size * sizeof(float), stream);
        das_kernel<true><<<NBLOCKS, THREADS, 0, stream>>>(rf, g, pr, p, out);
    }
}